// Round 8
// baseline (609.488 us; speedup 1.0000x reference)
//
#include <hip/hip_runtime.h>
#include <cmath>

#define HID 128

typedef __attribute__((ext_vector_type(8))) short bf16x8;
typedef __attribute__((ext_vector_type(4))) float f32x4;

__device__ __forceinline__ unsigned short f2bf(float f) {
    union { float f; unsigned int i; } c; c.f = f;
    unsigned int r = c.i + 0x7fffu + ((c.i >> 16) & 1u);
    return (unsigned short)(r >> 16);
}
__device__ __forceinline__ unsigned cvt_pk(float lo, float hi) {
    unsigned r;
    asm("v_cvt_pk_bf16_f32 %0, %1, %2" : "=v"(r) : "v"(lo), "v"(hi));
    return r;
}
__device__ __forceinline__ float silu_f(float v) {
    float t = __builtin_amdgcn_exp2f(-1.44269504f * v);
    return v * __builtin_amdgcn_rcpf(1.0f + t);
}
__device__ __forceinline__ float sigmoid_f(float v) {
    return __builtin_amdgcn_rcpf(1.0f + __builtin_amdgcn_exp2f(-1.44269504f * v));
}
typedef __fp16 fp16x2 __attribute__((ext_vector_type(2)));
__device__ __forceinline__ unsigned pkrtz(float lo, float hi) {
    union { fp16x2 h; unsigned u; } cv;
    cv.h = __builtin_amdgcn_cvt_pkrtz(lo, hi);
    return cv.u;
}
__device__ __forceinline__ void atomic_pk_add_f16_raw(void* p, unsigned u) {
    unsigned long long a = (unsigned long long)p;
    asm volatile("global_atomic_pk_add_f16 %0, %1, off" :: "v"(a), "v"(u) : "memory");
}

// ---------------------------------------------------------------------------
// Weight prep (unchanged): A-fragments of W^T.
// ---------------------------------------------------------------------------
__global__ __launch_bounds__(256) void egnn_prep(
    const float* __restrict__ We1, const float* __restrict__ We2,
    const float* __restrict__ Wc1, const float* __restrict__ Wn1,
    const float* __restrict__ Wn2,
    short* __restrict__ We1p, short* __restrict__ We2p, short* __restrict__ Wc1p,
    short* __restrict__ Wn1p, short* __restrict__ Wn2p)
{
    int t = blockIdx.x * 256 + threadIdx.x;
    int frag = t >> 6, lane = t & 63;
    if (frag >= 224) return;
    const float* W; short* dst; int KC, f;
    if (frag < 64)       { W = We1; dst = We1p; KC = 8; f = frag; }
    else if (frag < 96)  { W = We2; dst = We2p; KC = 4; f = frag - 64; }
    else if (frag < 128) { W = Wc1; dst = Wc1p; KC = 4; f = frag - 96; }
    else if (frag < 192) { W = Wn1; dst = Wn1p; KC = 8; f = frag - 128; }
    else                 { W = Wn2; dst = Wn2p; KC = 4; f = frag - 192; }
    int nt = f / KC, kc = f % KC;
    int n = nt * 16 + (lane & 15);
    short* d = dst + (((size_t)nt * KC + kc) * 64 + lane) * 8;
    #pragma unroll
    for (int j = 0; j < 8; ++j) {
        int k = kc * 32 + ((lane >> 4) << 2) + (j & 3) + ((j >> 2) << 4);
        d[j] = (short)f2bf(W[(size_t)k * HID + n]);
    }
}

// ---- h -> bf16 pack (halves gather bytes in edge/node staging) ----
__global__ __launch_bounds__(256) void egnn_hpack(
    const float* __restrict__ h, short* __restrict__ h16, int N)
{
    int t = blockIdx.x * 256 + threadIdx.x;
    if (t < N * 32) {
        float4 v = *(const float4*)(h + (size_t)t * 4);
        uint2 p; p.x = cvt_pk(v.x, v.y); p.y = cvt_pk(v.z, v.w);
        *(uint2*)(h16 + (size_t)t * 4) = p;
    }
}

// ---- CSR counting sort: count -> scan -> scatter ----
__global__ __launch_bounds__(256) void egnn_count(
    const int* __restrict__ ei, int E, int* __restrict__ cnt)
{
    int t = blockIdx.x * 256 + threadIdx.x;
    if (t < E) atomicAdd(&cnt[ei[E + t]], 1);
}

__global__ __launch_bounds__(1024) void egnn_scan(
    const int* __restrict__ cnt, int* __restrict__ cursor, int N)
{
    __shared__ int part[1024];
    int t = threadIdx.x;
    int chunk = (N + 1023) >> 10;
    int base = t * chunk;
    int s = 0;
    for (int i = 0; i < chunk; ++i) {
        int idx = base + i;
        if (idx < N) s += cnt[idx];
    }
    part[t] = s;
    __syncthreads();
    for (int off = 1; off < 1024; off <<= 1) {
        int u = (t >= off) ? part[t - off] : 0;
        __syncthreads();
        part[t] += u;
        __syncthreads();
    }
    int run = part[t] - s;          // exclusive prefix for this chunk
    for (int i = 0; i < chunk; ++i) {
        int idx = base + i;
        if (idx < N) { cursor[idx] = run; run += cnt[idx]; }
    }
}

__global__ __launch_bounds__(256) void egnn_scatter(
    const int* __restrict__ ei, int E, int* __restrict__ cursor,
    int2* __restrict__ sorted)
{
    int t = blockIdx.x * 256 + threadIdx.x;
    if (t < E) {
        int col = ei[E + t];
        int pos = atomicAdd(&cursor[col], 1);
        int2 rc; rc.x = ei[t]; rc.y = col;
        sorted[pos] = rc;
    }
}

// ---------------------------------------------------------------------------
// Edge kernel: 64 DEST-SORTED edges/block, 4 waves. Layers chain in-register.
// m aggregation: gated m (f32) -> LDS -> cross-wave reduce-by-key -> one
// pk-f16 atomic per (dest-segment, feature-pair): ~2.3 emits per 16 rows.
// ---------------------------------------------------------------------------
__global__ __launch_bounds__(256) void egnn_edge_mfma(
    const short* __restrict__ h16, const float* __restrict__ x,
    const int2* __restrict__ sorted, int E,
    const short* __restrict__ We1p, const float* __restrict__ We1,
    const float* __restrict__ be1,
    const short* __restrict__ We2p, const float* __restrict__ be2,
    const float* __restrict__ Wg, const float* __restrict__ bg,
    const short* __restrict__ Wc1p, const float* __restrict__ bc1,
    const float* __restrict__ Wc2, const float* __restrict__ bc2,
    short* __restrict__ m16, float* __restrict__ coord_aggr)
{
    __shared__ short sStage[64 * 256];          // 32KB; rows 512B
    __shared__ float s_be1[128], s_w256[128], s_be2[128];
    __shared__ float s_wg[128], s_bc1[128], s_wc2[128];
    __shared__ int   s_col[64], s_row[64];

    const int tid  = threadIdx.x;
    const int lane = tid & 63;
    const int w    = tid >> 6;
    const int l15  = lane & 15;
    const int g    = lane >> 4;
    const int e0   = blockIdx.x * 64;
    const int ne   = min(64, E - e0);

    if (tid < 64) {
        int slot = min(e0 + tid, E - 1);
        int2 rc = sorted[slot];
        s_row[tid] = rc.x;
        s_col[tid] = rc.y;
    }
    if (tid < 128) {
        s_be1[tid]  = be1[tid];
        s_w256[tid] = We1[(size_t)256 * HID + tid];
        s_be2[tid]  = be2[tid];
        s_wg[tid]   = Wg[tid];
        s_bc1[tid]  = bc1[tid];
        s_wc2[tid]  = Wc2[tid];
    }
    __syncthreads();

    // ---- stage msg^T rows from h16 (bf16, XOR swizzle): lane q covers
    // 8B = 4 features; q<32 -> h[col] half, q>=32 -> h[row] half.
    #pragma unroll
    for (int it = 0; it < 16; ++it) {
        int e = w + 4 * it;
        int q = lane;
        int node = (q < 32) ? s_col[e] : s_row[e];
        uint2 v = *(const uint2*)(h16 + (size_t)node * HID + (size_t)(q & 31) * 4);
        *(uint2*)((char*)sStage + e * 512 + ((q * 8) ^ ((e & 7) << 4))) = v;
    }

    // ---- per-lane edge geometry
    const int eloc = w * 16 + l15;
    const int nr = s_row[eloc], nc = s_col[eloc];
    float dx = x[nc * 3 + 0] - x[nr * 3 + 0];
    float dy = x[nc * 3 + 1] - x[nr * 3 + 1];
    float dz = x[nc * 3 + 2] - x[nr * 3 + 2];
    float dist = sqrtf(dx * dx + dy * dy + dz * dz);
    __syncthreads();

    const char* stageRow = (const char*)sStage + eloc * 512;
    const int sw = (eloc & 7) << 4;
    const bf16x8* A1 = (const bf16x8*)We1p;
    const bf16x8* A2 = (const bf16x8*)We2p;
    const bf16x8* A3 = (const bf16x8*)Wc1p;

    // ---- L1: K=256 (+ dist column folded into init)
    f32x4 acc[8];
    #pragma unroll
    for (int mt = 0; mt < 8; ++mt) {
        int f = mt * 16 + g * 4;
        #pragma unroll
        for (int r = 0; r < 4; ++r)
            acc[mt][r] = s_be1[f + r] + dist * s_w256[f + r];
    }
    #pragma unroll
    for (int kc = 0; kc < 8; ++kc) {
        int kb = kc * 64 + g * 8;
        uint2 lo = *(const uint2*)(stageRow + ((kb     ) ^ sw));
        uint2 hi = *(const uint2*)(stageRow + ((kb + 32) ^ sw));
        bf16x8 b; ((uint2*)&b)[0] = lo; ((uint2*)&b)[1] = hi;
        #pragma unroll
        for (int mt = 0; mt < 8; ++mt)
            acc[mt] = __builtin_amdgcn_mfma_f32_16x16x32_bf16(A1[(mt * 8 + kc) * 64 + lane], b, acc[mt], 0, 0, 0);
    }

    // ---- silu + pack B for L2
    bf16x8 Bn[4];
    #pragma unroll
    for (int kc = 0; kc < 4; ++kc) {
        unsigned* d = (unsigned*)&Bn[kc];
        d[0] = cvt_pk(silu_f(acc[2 * kc][0]),     silu_f(acc[2 * kc][1]));
        d[1] = cvt_pk(silu_f(acc[2 * kc][2]),     silu_f(acc[2 * kc][3]));
        d[2] = cvt_pk(silu_f(acc[2 * kc + 1][0]), silu_f(acc[2 * kc + 1][1]));
        d[3] = cvt_pk(silu_f(acc[2 * kc + 1][2]), silu_f(acc[2 * kc + 1][3]));
    }

    // ---- L2
    f32x4 acc2[8];
    #pragma unroll
    for (int mt = 0; mt < 8; ++mt) {
        int f = mt * 16 + g * 4;
        #pragma unroll
        for (int r = 0; r < 4; ++r) acc2[mt][r] = s_be2[f + r];
    }
    #pragma unroll
    for (int kc = 0; kc < 4; ++kc)
        #pragma unroll
        for (int mt = 0; mt < 8; ++mt)
            acc2[mt] = __builtin_amdgcn_mfma_f32_16x16x32_bf16(A2[(mt * 4 + kc) * 64 + lane], Bn[kc], acc2[mt], 0, 0, 0);

    // ---- silu + gate partial dot
    float gp = 0.f;
    #pragma unroll
    for (int mt = 0; mt < 8; ++mt) {
        int f = mt * 16 + g * 4;
        #pragma unroll
        for (int r = 0; r < 4; ++r) {
            float sv = silu_f(acc2[mt][r]);
            acc2[mt][r] = sv;
            gp += sv * s_wg[f + r];
        }
    }
    gp += __shfl_xor(gp, 16, 64);
    gp += __shfl_xor(gp, 32, 64);
    float gate = sigmoid_f(gp + bg[0]);
    gate *= (eloc < ne) ? 1.0f : 0.0f;      // zero pad-slot payloads

    // ---- apply gate; write gated m (f32, full 512B row) to LDS
    #pragma unroll
    for (int mt = 0; mt < 8; ++mt) {
        f32x4 v;
        #pragma unroll
        for (int r = 0; r < 4; ++r) { acc2[mt][r] *= gate; v[r] = acc2[mt][r]; }
        *(f32x4*)((char*)sStage + eloc * 512 + ((g * 16 + mt * 64) ^ sw)) = v;
    }

    // ---- pack gated m as B for L3 (from registers)
    bf16x8 B3[4];
    #pragma unroll
    for (int kc = 0; kc < 4; ++kc) {
        unsigned* d = (unsigned*)&B3[kc];
        d[0] = cvt_pk(acc2[2 * kc][0],     acc2[2 * kc][1]);
        d[1] = cvt_pk(acc2[2 * kc][2],     acc2[2 * kc][3]);
        d[2] = cvt_pk(acc2[2 * kc + 1][0], acc2[2 * kc + 1][1]);
        d[3] = cvt_pk(acc2[2 * kc + 1][2], acc2[2 * kc + 1][3]);
    }

    __syncthreads();

    // ---- cross-wave reduce-by-key over dest-sorted rows.
    // Thread (fp, rg): features {2fp, 2fp+1}, rows [16rg, 16rg+16).
    // Branches are wave-uniform (all lanes of a wave share rg).
    {
        int fp = tid & 63;
        int rg = tid >> 6;
        float ax = 0.f, ay = 0.f;
        int d = s_col[rg * 16];
        #pragma unroll
        for (int i = 0; i < 16; ++i) {
            int e = rg * 16 + i;
            float2 v = *(const float2*)((const char*)sStage + e * 512 + ((fp * 8) ^ ((e & 7) << 4)));
            ax += v.x; ay += v.y;
            int dn = (i < 15) ? s_col[e + 1] : -1;
            if (dn != d) {
                atomic_pk_add_f16_raw(m16 + (size_t)d * HID + fp * 2, pkrtz(ax, ay));
                ax = 0.f; ay = 0.f; d = dn;
            }
        }
    }

    // ---- L3 (registers + read-only LDS consts; overlaps atomic drain)
    f32x4 acc3[8];
    #pragma unroll
    for (int mt = 0; mt < 8; ++mt) {
        int f = mt * 16 + g * 4;
        #pragma unroll
        for (int r = 0; r < 4; ++r) acc3[mt][r] = s_bc1[f + r];
    }
    #pragma unroll
    for (int kc = 0; kc < 4; ++kc)
        #pragma unroll
        for (int mt = 0; mt < 8; ++mt)
            acc3[mt] = __builtin_amdgcn_mfma_f32_16x16x32_bf16(A3[(mt * 4 + kc) * 64 + lane], B3[kc], acc3[mt], 0, 0, 0);

    // ---- coord weight dot + scatter
    float cwp = 0.f;
    #pragma unroll
    for (int mt = 0; mt < 8; ++mt) {
        int f = mt * 16 + g * 4;
        #pragma unroll
        for (int r = 0; r < 4; ++r)
            cwp += silu_f(acc3[mt][r]) * s_wc2[f + r];
    }
    cwp += __shfl_xor(cwp, 16, 64);
    cwp += __shfl_xor(cwp, 32, 64);
    float cw = cwp + bc2[0];
    if (g == 0 && eloc < ne) {
        atomicAdd(&coord_aggr[nc * 3 + 0], dx * cw);
        atomicAdd(&coord_aggr[nc * 3 + 1], dy * cw);
        atomicAdd(&coord_aggr[nc * 3 + 2], dz * cw);
    }
}

// ---------------------------------------------------------------------------
// Node kernel: transposed structure, 64 nodes/block; h staged from h16,
// m read as f16; residual read stays f32.
// ---------------------------------------------------------------------------
__global__ __launch_bounds__(256) void egnn_node_mfma(
    const float* __restrict__ h, const short* __restrict__ h16,
    const float* __restrict__ x,
    const short* __restrict__ m16, const float* __restrict__ coord_aggr,
    const short* __restrict__ Wn1p, const float* __restrict__ bn1,
    const short* __restrict__ Wn2p, const float* __restrict__ bn2,
    float* __restrict__ h_out, float* __restrict__ x_out, int N)
{
    __shared__ short sStage[64 * 256];
    __shared__ float s_bn1[128], s_bn2[128];

    const int tid  = threadIdx.x;
    const int lane = tid & 63;
    const int w    = tid >> 6;
    const int l15  = lane & 15;
    const int g    = lane >> 4;
    const int n0   = blockIdx.x * 64;

    if (tid < 128) { s_bn1[tid] = bn1[tid]; s_bn2[tid] = bn2[tid]; }

    if (tid < 192) {
        int gi = n0 * 3 + tid;
        if (gi < 3 * N) x_out[gi] = x[gi] + coord_aggr[gi];
    }

    #pragma unroll
    for (int it = 0; it < 16; ++it) {
        int e = w + 4 * it;
        int q = lane;
        int node = min(n0 + e, N - 1);
        uint2 pk;
        if (q < 32) {
            pk = *(const uint2*)(h16 + (size_t)node * HID + (size_t)q * 4);
        } else {
            uint2 hv = *(const uint2*)((const char*)m16 + (size_t)node * 256 + (size_t)(q & 31) * 8);
            const __fp16* hp = (const __fp16*)&hv;
            pk.x = cvt_pk((float)hp[0], (float)hp[1]);
            pk.y = cvt_pk((float)hp[2], (float)hp[3]);
        }
        *(uint2*)((char*)sStage + e * 512 + ((q * 8) ^ ((e & 7) << 4))) = pk;
    }
    __syncthreads();

    const int nloc = w * 16 + l15;
    const int node = n0 + nloc;
    const char* stageRow = (const char*)sStage + nloc * 512;
    const int sw = (nloc & 7) << 4;
    const bf16x8* A1 = (const bf16x8*)Wn1p;
    const bf16x8* A2 = (const bf16x8*)Wn2p;

    f32x4 acc[8];
    #pragma unroll
    for (int mt = 0; mt < 8; ++mt) {
        int f = mt * 16 + g * 4;
        #pragma unroll
        for (int r = 0; r < 4; ++r) acc[mt][r] = s_bn1[f + r];
    }
    #pragma unroll
    for (int kc = 0; kc < 8; ++kc) {
        int kb = kc * 64 + g * 8;
        uint2 lo = *(const uint2*)(stageRow + ((kb     ) ^ sw));
        uint2 hi = *(const uint2*)(stageRow + ((kb + 32) ^ sw));
        bf16x8 b; ((uint2*)&b)[0] = lo; ((uint2*)&b)[1] = hi;
        #pragma unroll
        for (int mt = 0; mt < 8; ++mt)
            acc[mt] = __builtin_amdgcn_mfma_f32_16x16x32_bf16(A1[(mt * 8 + kc) * 64 + lane], b, acc[mt], 0, 0, 0);
    }

    bf16x8 Bn[4];
    #pragma unroll
    for (int kc = 0; kc < 4; ++kc) {
        unsigned* d = (unsigned*)&Bn[kc];
        d[0] = cvt_pk(silu_f(acc[2 * kc][0]),     silu_f(acc[2 * kc][1]));
        d[1] = cvt_pk(silu_f(acc[2 * kc][2]),     silu_f(acc[2 * kc][3]));
        d[2] = cvt_pk(silu_f(acc[2 * kc + 1][0]), silu_f(acc[2 * kc + 1][1]));
        d[3] = cvt_pk(silu_f(acc[2 * kc + 1][2]), silu_f(acc[2 * kc + 1][3]));
    }

    f32x4 acc2[8];
    #pragma unroll
    for (int mt = 0; mt < 8; ++mt) {
        int f = mt * 16 + g * 4;
        #pragma unroll
        for (int r = 0; r < 4; ++r) acc2[mt][r] = s_bn2[f + r];
    }
    #pragma unroll
    for (int kc = 0; kc < 4; ++kc)
        #pragma unroll
        for (int mt = 0; mt < 8; ++mt)
            acc2[mt] = __builtin_amdgcn_mfma_f32_16x16x32_bf16(A2[(mt * 4 + kc) * 64 + lane], Bn[kc], acc2[mt], 0, 0, 0);

    if (node < N) {
        #pragma unroll
        for (int mt = 0; mt < 8; ++mt) {
            size_t base = (size_t)node * HID + mt * 16 + g * 4;
            float4 hres = *(const float4*)&h[base];
            float4 o;
            o.x = acc2[mt][0] + hres.x;
            o.y = acc2[mt][1] + hres.y;
            o.z = acc2[mt][2] + hres.z;
            o.w = acc2[mt][3] + hres.w;
            *(float4*)&h_out[base] = o;
        }
    }
}

extern "C" void kernel_launch(void* const* d_in, const int* in_sizes, int n_in,
                              void* d_out, int out_size, void* d_ws, size_t ws_size,
                              hipStream_t stream) {
    const float* h   = (const float*)d_in[0];
    const float* x   = (const float*)d_in[1];
    const int*   ei  = (const int*)d_in[2];
    const float* We1 = (const float*)d_in[3];
    const float* be1 = (const float*)d_in[4];
    const float* We2 = (const float*)d_in[5];
    const float* be2 = (const float*)d_in[6];
    const float* Wg  = (const float*)d_in[7];
    const float* bg  = (const float*)d_in[8];
    const float* Wn1 = (const float*)d_in[9];
    const float* bn1 = (const float*)d_in[10];
    const float* Wn2 = (const float*)d_in[11];
    const float* bn2 = (const float*)d_in[12];
    const float* Wc1 = (const float*)d_in[13];
    const float* bc1 = (const float*)d_in[14];
    const float* Wc2 = (const float*)d_in[15];
    const float* bc2 = (const float*)d_in[16];

    const int N = in_sizes[0] / HID;
    const int E = in_sizes[2] / 2;

    // workspace layout
    char* p = (char*)d_ws;
    short* m16        = (short*)p;  p += (size_t)N * 256;   // N*128 f16
    float* coord_aggr = (float*)p;  p += (size_t)N * 12;    // N*3 f32
    int*   cnt        = (int*)p;    p += (size_t)N * 4;
    // ---- memset covers [d_ws, p) = N*272 bytes ----
    int*   cursor     = (int*)p;    p += (size_t)N * 4;
    p = (char*)(((uintptr_t)p + 7) & ~(uintptr_t)7);
    int2*  sorted     = (int2*)p;   p += (size_t)E * 8;
    short* h16        = (short*)p;  p += (size_t)N * 256;   // N*128 bf16
    short* We1p       = (short*)p;  p += 256 * 128 * 2;
    short* We2p       = (short*)p;  p += 128 * 128 * 2;
    short* Wc1p       = (short*)p;  p += 128 * 128 * 2;
    short* Wn1p       = (short*)p;  p += 256 * 128 * 2;
    short* Wn2p       = (short*)p;  p += 128 * 128 * 2;

    (void)hipMemsetAsync(d_ws, 0, (size_t)N * 272, stream);

    float* h_out = (float*)d_out;
    float* x_out = h_out + (size_t)N * HID;

    egnn_prep<<<dim3(56), dim3(256), 0, stream>>>(
        We1, We2, Wc1, Wn1, Wn2, We1p, We2p, Wc1p, Wn1p, Wn2p);
    egnn_hpack<<<dim3((N * 32 + 255) / 256), dim3(256), 0, stream>>>(h, h16, N);
    egnn_count<<<dim3((E + 255) / 256), dim3(256), 0, stream>>>(ei, E, cnt);
    egnn_scan<<<dim3(1), dim3(1024), 0, stream>>>(cnt, cursor, N);
    egnn_scatter<<<dim3((E + 255) / 256), dim3(256), 0, stream>>>(ei, E, cursor, sorted);
    egnn_edge_mfma<<<dim3((E + 63) / 64), dim3(256), 0, stream>>>(
        h16, x, sorted, E, We1p, We1, be1, We2p, be2, Wg, bg, Wc1p, bc1, Wc2, bc2,
        m16, coord_aggr);
    egnn_node_mfma<<<dim3((N + 63) / 64), dim3(256), 0, stream>>>(
        h, h16, x, m16, coord_aggr, Wn1p, bn1, Wn2p, bn2, h_out, x_out, N);
}

// Round 9
// 537.267 us; speedup vs baseline: 1.1344x; 1.1344x over previous
//
#include <hip/hip_runtime.h>
#include <cmath>

#define HID 128

typedef __attribute__((ext_vector_type(8))) short bf16x8;
typedef __attribute__((ext_vector_type(4))) float f32x4;

__device__ __forceinline__ unsigned short f2bf(float f) {
    union { float f; unsigned int i; } c; c.f = f;
    unsigned int r = c.i + 0x7fffu + ((c.i >> 16) & 1u);
    return (unsigned short)(r >> 16);
}
__device__ __forceinline__ unsigned cvt_pk(float lo, float hi) {
    unsigned r;
    asm("v_cvt_pk_bf16_f32 %0, %1, %2" : "=v"(r) : "v"(lo), "v"(hi));
    return r;
}
__device__ __forceinline__ float bflo(unsigned u) {
    union { unsigned i; float f; } c; c.i = u << 16; return c.f;
}
__device__ __forceinline__ float bfhi(unsigned u) {
    union { unsigned i; float f; } c; c.i = u & 0xffff0000u; return c.f;
}
__device__ __forceinline__ float silu_f(float v) {
    float t = __builtin_amdgcn_exp2f(-1.44269504f * v);
    return v * __builtin_amdgcn_rcpf(1.0f + t);
}
__device__ __forceinline__ float sigmoid_f(float v) {
    return __builtin_amdgcn_rcpf(1.0f + __builtin_amdgcn_exp2f(-1.44269504f * v));
}
typedef __fp16 fp16x2 __attribute__((ext_vector_type(2)));
__device__ __forceinline__ unsigned pkrtz(float lo, float hi) {
    union { fp16x2 h; unsigned u; } cv;
    cv.h = __builtin_amdgcn_cvt_pkrtz(lo, hi);
    return cv.u;
}
// volatile but NO memory clobber: lets compiler overlap L3 loads/MFMAs with drain
__device__ __forceinline__ void atomic_pk_add_f16_raw(void* p, unsigned u) {
    unsigned long long a = (unsigned long long)p;
    asm volatile("global_atomic_pk_add_f16 %0, %1, off" :: "v"(a), "v"(u));
}

// ---------------------------------------------------------------------------
// Weight prep: A-fragments of W^T (unchanged mapping).
// ---------------------------------------------------------------------------
__global__ __launch_bounds__(256) void egnn_prep(
    const float* __restrict__ We1, const float* __restrict__ We2,
    const float* __restrict__ Wc1, const float* __restrict__ Wn1,
    const float* __restrict__ Wn2,
    short* __restrict__ We1p, short* __restrict__ We2p, short* __restrict__ Wc1p,
    short* __restrict__ Wn1p, short* __restrict__ Wn2p)
{
    int t = blockIdx.x * 256 + threadIdx.x;
    int frag = t >> 6, lane = t & 63;
    if (frag >= 224) return;
    const float* W; short* dst; int KC, f;
    if (frag < 64)       { W = We1; dst = We1p; KC = 8; f = frag; }
    else if (frag < 96)  { W = We2; dst = We2p; KC = 4; f = frag - 64; }
    else if (frag < 128) { W = Wc1; dst = Wc1p; KC = 4; f = frag - 96; }
    else if (frag < 192) { W = Wn1; dst = Wn1p; KC = 8; f = frag - 128; }
    else                 { W = Wn2; dst = Wn2p; KC = 4; f = frag - 192; }
    int nt = f / KC, kc = f % KC;
    int n = nt * 16 + (lane & 15);
    short* d = dst + (((size_t)nt * KC + kc) * 64 + lane) * 8;
    #pragma unroll
    for (int j = 0; j < 8; ++j) {
        int k = kc * 32 + ((lane >> 4) << 2) + (j & 3) + ((j >> 2) << 4);
        d[j] = (short)f2bf(W[(size_t)k * HID + n]);
    }
}

// ---- h -> bf16 pack ----
__global__ __launch_bounds__(256) void egnn_hpack(
    const float* __restrict__ h, short* __restrict__ h16, int N)
{
    int t = blockIdx.x * 256 + threadIdx.x;
    if (t < N * 32) {
        float4 v = *(const float4*)(h + (size_t)t * 4);
        uint2 p; p.x = cvt_pk(v.x, v.y); p.y = cvt_pk(v.z, v.w);
        *(uint2*)(h16 + (size_t)t * 4) = p;
    }
}

// ---------------------------------------------------------------------------
// Edge kernel: 64 edges/block, 4 waves; wave w owns edges w*16..w*16+15.
// mt-pair-outer restructure: peak live regs ~110 -> 3 waves/SIMD.
// ---------------------------------------------------------------------------
__global__ __launch_bounds__(256, 3) void egnn_edge_mfma(
    const short* __restrict__ h16, const float* __restrict__ x,
    const int* __restrict__ ei, int E,
    const short* __restrict__ We1p, const float* __restrict__ We1,
    const float* __restrict__ be1,
    const short* __restrict__ We2p, const float* __restrict__ be2,
    const float* __restrict__ Wg, const float* __restrict__ bg,
    const short* __restrict__ Wc1p, const float* __restrict__ bc1,
    const float* __restrict__ Wc2, const float* __restrict__ bc2,
    short* __restrict__ m16, float* __restrict__ coord_aggr)
{
    __shared__ short sStage[64 * 256];          // 32KB; rows 512B, wave-private
    __shared__ float s_be1[128], s_w256[128], s_be2[128];
    __shared__ float s_wg[128], s_bc1[128], s_wc2[128];
    __shared__ int   s_col[64], s_row[64];

    const int tid  = threadIdx.x;
    const int lane = tid & 63;
    const int w    = tid >> 6;
    const int l15  = lane & 15;
    const int g    = lane >> 4;
    const int e0   = blockIdx.x * 64;
    const int ne   = min(64, E - e0);

    if (tid < 64) {
        s_row[tid] = ei[e0 + tid];
        s_col[tid] = ei[E + e0 + tid];
    }
    if (tid < 128) {
        s_be1[tid]  = be1[tid];
        s_w256[tid] = We1[(size_t)256 * HID + tid];
        s_be2[tid]  = be2[tid];
        s_wg[tid]   = Wg[tid];
        s_bc1[tid]  = bc1[tid];
        s_wc2[tid]  = Wc2[tid];
    }
    __syncthreads();

    // ---- stage msg^T rows from h16 (8B/lane, XOR swizzle)
    #pragma unroll
    for (int it = 0; it < 16; ++it) {
        int e = w + 4 * it;
        int q = lane;
        int node = (q < 32) ? s_col[e] : s_row[e];
        uint2 v = *(const uint2*)(h16 + (size_t)node * HID + (size_t)(q & 31) * 4);
        *(uint2*)((char*)sStage + e * 512 + ((q * 8) ^ ((e & 7) << 4))) = v;
    }

    // ---- per-lane edge geometry
    const int eloc = w * 16 + l15;
    const int nr = s_row[eloc], nc = s_col[eloc];
    float dx = x[nc * 3 + 0] - x[nr * 3 + 0];
    float dy = x[nc * 3 + 1] - x[nr * 3 + 1];
    float dz = x[nc * 3 + 2] - x[nr * 3 + 2];
    float dist = sqrtf(dx * dx + dy * dy + dz * dz);
    __syncthreads();

    const char* stageRow = (const char*)sStage + eloc * 512;
    const int sw = (eloc & 7) << 4;
    const bf16x8* A1 = (const bf16x8*)We1p;
    const bf16x8* A2 = (const bf16x8*)We2p;
    const bf16x8* A3 = (const bf16x8*)Wc1p;

    // ---- hoist the 8 B-fragments (this edge's msg row) once
    bf16x8 b[8];
    #pragma unroll
    for (int kc = 0; kc < 8; ++kc) {
        int kb = kc * 64 + g * 8;
        uint2 lo = *(const uint2*)(stageRow + ((kb     ) ^ sw));
        uint2 hi = *(const uint2*)(stageRow + ((kb + 32) ^ sw));
        ((uint2*)&b[kc])[0] = lo; ((uint2*)&b[kc])[1] = hi;
    }

    // ---- L1: K=256, mt-pair loop; output packed bf16 Bn[4]
    bf16x8 Bn[4];
    #pragma unroll
    for (int j = 0; j < 4; ++j) {
        int f0 = (2 * j) * 16 + g * 4;
        int f1 = f0 + 16;
        f32x4 aa, ab;
        #pragma unroll
        for (int r = 0; r < 4; ++r) {
            aa[r] = s_be1[f0 + r] + dist * s_w256[f0 + r];
            ab[r] = s_be1[f1 + r] + dist * s_w256[f1 + r];
        }
        #pragma unroll
        for (int kc = 0; kc < 8; ++kc) {
            aa = __builtin_amdgcn_mfma_f32_16x16x32_bf16(A1[((2 * j) * 8 + kc) * 64 + lane], b[kc], aa, 0, 0, 0);
            ab = __builtin_amdgcn_mfma_f32_16x16x32_bf16(A1[((2 * j + 1) * 8 + kc) * 64 + lane], b[kc], ab, 0, 0, 0);
        }
        unsigned* d = (unsigned*)&Bn[j];
        d[0] = cvt_pk(silu_f(aa[0]), silu_f(aa[1]));
        d[1] = cvt_pk(silu_f(aa[2]), silu_f(aa[3]));
        d[2] = cvt_pk(silu_f(ab[0]), silu_f(ab[1]));
        d[3] = cvt_pk(silu_f(ab[2]), silu_f(ab[3]));
    }

    // ---- L2: K=128, mt-pair loop; output packed UNGATED bf16 Pn[4] + gate dot
    bf16x8 Pn[4];
    float gp = 0.f;
    #pragma unroll
    for (int j = 0; j < 4; ++j) {
        int f0 = (2 * j) * 16 + g * 4;
        int f1 = f0 + 16;
        f32x4 aa, ab;
        #pragma unroll
        for (int r = 0; r < 4; ++r) { aa[r] = s_be2[f0 + r]; ab[r] = s_be2[f1 + r]; }
        #pragma unroll
        for (int kc = 0; kc < 4; ++kc) {
            aa = __builtin_amdgcn_mfma_f32_16x16x32_bf16(A2[((2 * j) * 4 + kc) * 64 + lane], Bn[kc], aa, 0, 0, 0);
            ab = __builtin_amdgcn_mfma_f32_16x16x32_bf16(A2[((2 * j + 1) * 4 + kc) * 64 + lane], Bn[kc], ab, 0, 0, 0);
        }
        float sv[8];
        #pragma unroll
        for (int r = 0; r < 4; ++r) {
            sv[r]     = silu_f(aa[r]);
            sv[4 + r] = silu_f(ab[r]);
            gp += sv[r] * s_wg[f0 + r] + sv[4 + r] * s_wg[f1 + r];
        }
        unsigned* d = (unsigned*)&Pn[j];
        d[0] = cvt_pk(sv[0], sv[1]);
        d[1] = cvt_pk(sv[2], sv[3]);
        d[2] = cvt_pk(sv[4], sv[5]);
        d[3] = cvt_pk(sv[6], sv[7]);
    }
    gp += __shfl_xor(gp, 16, 64);
    gp += __shfl_xor(gp, 32, 64);
    float gate = sigmoid_f(gp + bg[0]);
    gate *= (eloc < ne) ? 1.0f : 0.0f;      // zero pad-slot payloads

    // ---- gated pass in packed domain: Pn -> B3 (bf16) + f16 words to LDS
    bf16x8 B3[4];
    #pragma unroll
    for (int j = 0; j < 4; ++j) {
        const unsigned* s = (const unsigned*)&Pn[j];
        unsigned* d = (unsigned*)&B3[j];
        uint2 w0, w1;
        {
            float glo = bflo(s[0]) * gate, ghi = bfhi(s[0]) * gate;
            d[0] = cvt_pk(glo, ghi); w0.x = pkrtz(glo, ghi);
        }
        {
            float glo = bflo(s[1]) * gate, ghi = bfhi(s[1]) * gate;
            d[1] = cvt_pk(glo, ghi); w0.y = pkrtz(glo, ghi);
        }
        {
            float glo = bflo(s[2]) * gate, ghi = bfhi(s[2]) * gate;
            d[2] = cvt_pk(glo, ghi); w1.x = pkrtz(glo, ghi);
        }
        {
            float glo = bflo(s[3]) * gate, ghi = bfhi(s[3]) * gate;
            d[3] = cvt_pk(glo, ghi); w1.y = pkrtz(glo, ghi);
        }
        // mt=2j at byte (2j)*32 + g*8 ; mt=2j+1 at (2j+1)*32 + g*8
        *(uint2*)((char*)sStage + eloc * 512 + (((2 * j) * 32 + g * 8) ^ sw))     = w0;
        *(uint2*)((char*)sStage + eloc * 512 + (((2 * j + 1) * 32 + g * 8) ^ sw)) = w1;
    }

    // ---- dense m scatter: one pk-f16 atomic per (edge, lane) covering
    // features {2*lane, 2*lane+1}; 64 ops / 4 lines per edge.
    #pragma unroll
    for (int i = 0; i < 16; ++i) {
        int e = w * 16 + i;
        int c = s_col[e];
        int swE = (e & 7) << 4;
        unsigned v = *(const unsigned*)((const char*)sStage + e * 512 + ((lane * 4) ^ swE));
        atomic_pk_add_f16_raw(m16 + (size_t)c * HID + lane * 2, v);
    }

    // ---- L3: K=128, mt-pair loop; consume into coord-weight dot
    float cwp = 0.f;
    #pragma unroll
    for (int j = 0; j < 4; ++j) {
        int f0 = (2 * j) * 16 + g * 4;
        int f1 = f0 + 16;
        f32x4 aa, ab;
        #pragma unroll
        for (int r = 0; r < 4; ++r) { aa[r] = s_bc1[f0 + r]; ab[r] = s_bc1[f1 + r]; }
        #pragma unroll
        for (int kc = 0; kc < 4; ++kc) {
            aa = __builtin_amdgcn_mfma_f32_16x16x32_bf16(A3[((2 * j) * 4 + kc) * 64 + lane], B3[kc], aa, 0, 0, 0);
            ab = __builtin_amdgcn_mfma_f32_16x16x32_bf16(A3[((2 * j + 1) * 4 + kc) * 64 + lane], B3[kc], ab, 0, 0, 0);
        }
        #pragma unroll
        for (int r = 0; r < 4; ++r)
            cwp += silu_f(aa[r]) * s_wc2[f0 + r] + silu_f(ab[r]) * s_wc2[f1 + r];
    }
    cwp += __shfl_xor(cwp, 16, 64);
    cwp += __shfl_xor(cwp, 32, 64);
    float cw = cwp + bc2[0];
    if (g == 0 && eloc < ne) {
        atomicAdd(&coord_aggr[nc * 3 + 0], dx * cw);
        atomicAdd(&coord_aggr[nc * 3 + 1], dy * cw);
        atomicAdd(&coord_aggr[nc * 3 + 2], dz * cw);
    }
}

// ---------------------------------------------------------------------------
// Node kernel: transposed structure, 64 nodes/block; h staged from h16,
// m read as f16; residual read stays f32. (unchanged)
// ---------------------------------------------------------------------------
__global__ __launch_bounds__(256) void egnn_node_mfma(
    const float* __restrict__ h, const short* __restrict__ h16,
    const float* __restrict__ x,
    const short* __restrict__ m16, const float* __restrict__ coord_aggr,
    const short* __restrict__ Wn1p, const float* __restrict__ bn1,
    const short* __restrict__ Wn2p, const float* __restrict__ bn2,
    float* __restrict__ h_out, float* __restrict__ x_out, int N)
{
    __shared__ short sStage[64 * 256];
    __shared__ float s_bn1[128], s_bn2[128];

    const int tid  = threadIdx.x;
    const int lane = tid & 63;
    const int w    = tid >> 6;
    const int l15  = lane & 15;
    const int g    = lane >> 4;
    const int n0   = blockIdx.x * 64;

    if (tid < 128) { s_bn1[tid] = bn1[tid]; s_bn2[tid] = bn2[tid]; }

    if (tid < 192) {
        int gi = n0 * 3 + tid;
        if (gi < 3 * N) x_out[gi] = x[gi] + coord_aggr[gi];
    }

    #pragma unroll
    for (int it = 0; it < 16; ++it) {
        int e = w + 4 * it;
        int q = lane;
        int node = min(n0 + e, N - 1);
        uint2 pk;
        if (q < 32) {
            pk = *(const uint2*)(h16 + (size_t)node * HID + (size_t)q * 4);
        } else {
            uint2 hv = *(const uint2*)((const char*)m16 + (size_t)node * 256 + (size_t)(q & 31) * 8);
            const __fp16* hp = (const __fp16*)&hv;
            pk.x = cvt_pk((float)hp[0], (float)hp[1]);
            pk.y = cvt_pk((float)hp[2], (float)hp[3]);
        }
        *(uint2*)((char*)sStage + e * 512 + ((q * 8) ^ ((e & 7) << 4))) = pk;
    }
    __syncthreads();

    const int nloc = w * 16 + l15;
    const int node = n0 + nloc;
    const char* stageRow = (const char*)sStage + nloc * 512;
    const int sw = (nloc & 7) << 4;
    const bf16x8* A1 = (const bf16x8*)Wn1p;
    const bf16x8* A2 = (const bf16x8*)Wn2p;

    f32x4 acc[8];
    #pragma unroll
    for (int mt = 0; mt < 8; ++mt) {
        int f = mt * 16 + g * 4;
        #pragma unroll
        for (int r = 0; r < 4; ++r) acc[mt][r] = s_bn1[f + r];
    }
    #pragma unroll
    for (int kc = 0; kc < 8; ++kc) {
        int kb = kc * 64 + g * 8;
        uint2 lo = *(const uint2*)(stageRow + ((kb     ) ^ sw));
        uint2 hi = *(const uint2*)(stageRow + ((kb + 32) ^ sw));
        bf16x8 b; ((uint2*)&b)[0] = lo; ((uint2*)&b)[1] = hi;
        #pragma unroll
        for (int mt = 0; mt < 8; ++mt)
            acc[mt] = __builtin_amdgcn_mfma_f32_16x16x32_bf16(A1[(mt * 8 + kc) * 64 + lane], b, acc[mt], 0, 0, 0);
    }

    bf16x8 Bn[4];
    #pragma unroll
    for (int kc = 0; kc < 4; ++kc) {
        unsigned* d = (unsigned*)&Bn[kc];
        d[0] = cvt_pk(silu_f(acc[2 * kc][0]),     silu_f(acc[2 * kc][1]));
        d[1] = cvt_pk(silu_f(acc[2 * kc][2]),     silu_f(acc[2 * kc][3]));
        d[2] = cvt_pk(silu_f(acc[2 * kc + 1][0]), silu_f(acc[2 * kc + 1][1]));
        d[3] = cvt_pk(silu_f(acc[2 * kc + 1][2]), silu_f(acc[2 * kc + 1][3]));
    }

    f32x4 acc2[8];
    #pragma unroll
    for (int mt = 0; mt < 8; ++mt) {
        int f = mt * 16 + g * 4;
        #pragma unroll
        for (int r = 0; r < 4; ++r) acc2[mt][r] = s_bn2[f + r];
    }
    #pragma unroll
    for (int kc = 0; kc < 4; ++kc)
        #pragma unroll
        for (int mt = 0; mt < 8; ++mt)
            acc2[mt] = __builtin_amdgcn_mfma_f32_16x16x32_bf16(A2[(mt * 4 + kc) * 64 + lane], Bn[kc], acc2[mt], 0, 0, 0);

    if (node < N) {
        #pragma unroll
        for (int mt = 0; mt < 8; ++mt) {
            size_t base = (size_t)node * HID + mt * 16 + g * 4;
            float4 hres = *(const float4*)&h[base];
            float4 o;
            o.x = acc2[mt][0] + hres.x;
            o.y = acc2[mt][1] + hres.y;
            o.z = acc2[mt][2] + hres.z;
            o.w = acc2[mt][3] + hres.w;
            *(float4*)&h_out[base] = o;
        }
    }
}

extern "C" void kernel_launch(void* const* d_in, const int* in_sizes, int n_in,
                              void* d_out, int out_size, void* d_ws, size_t ws_size,
                              hipStream_t stream) {
    const float* h   = (const float*)d_in[0];
    const float* x   = (const float*)d_in[1];
    const int*   ei  = (const int*)d_in[2];
    const float* We1 = (const float*)d_in[3];
    const float* be1 = (const float*)d_in[4];
    const float* We2 = (const float*)d_in[5];
    const float* be2 = (const float*)d_in[6];
    const float* Wg  = (const float*)d_in[7];
    const float* bg  = (const float*)d_in[8];
    const float* Wn1 = (const float*)d_in[9];
    const float* bn1 = (const float*)d_in[10];
    const float* Wn2 = (const float*)d_in[11];
    const float* bn2 = (const float*)d_in[12];
    const float* Wc1 = (const float*)d_in[13];
    const float* bc1 = (const float*)d_in[14];
    const float* Wc2 = (const float*)d_in[15];
    const float* bc2 = (const float*)d_in[16];

    const int N = in_sizes[0] / HID;
    const int E = in_sizes[2] / 2;

    // workspace layout
    char* p = (char*)d_ws;
    short* m16        = (short*)p;  p += (size_t)N * 256;   // N*128 f16
    float* coord_aggr = (float*)p;  p += (size_t)N * 12;    // N*3 f32
    // ---- memset covers [d_ws, p) = N*268 bytes ----
    short* h16        = (short*)p;  p += (size_t)N * 256;   // N*128 bf16
    short* We1p       = (short*)p;  p += 256 * 128 * 2;
    short* We2p       = (short*)p;  p += 128 * 128 * 2;
    short* Wc1p       = (short*)p;  p += 128 * 128 * 2;
    short* Wn1p       = (short*)p;  p += 256 * 128 * 2;
    short* Wn2p       = (short*)p;  p += 128 * 128 * 2;

    (void)hipMemsetAsync(d_ws, 0, (size_t)N * 268, stream);

    float* h_out = (float*)d_out;
    float* x_out = h_out + (size_t)N * HID;

    egnn_prep<<<dim3(56), dim3(256), 0, stream>>>(
        We1, We2, Wc1, Wn1, Wn2, We1p, We2p, Wc1p, Wn1p, Wn2p);
    egnn_hpack<<<dim3((N * 32 + 255) / 256), dim3(256), 0, stream>>>(h, h16, N);
    egnn_edge_mfma<<<dim3((E + 63) / 64), dim3(256), 0, stream>>>(
        h16, x, ei, E, We1p, We1, be1, We2p, be2, Wg, bg, Wc1p, bc1, Wc2, bc2,
        m16, coord_aggr);
    egnn_node_mfma<<<dim3((N + 63) / 64), dim3(256), 0, stream>>>(
        h, h16, x, m16, coord_aggr, Wn1p, bn1, Wn2p, bn2, h_out, x_out, N);
}

// Round 10
// 492.417 us; speedup vs baseline: 1.2377x; 1.0911x over previous
//
#include <hip/hip_runtime.h>
#include <cmath>

#define HID 128

typedef __attribute__((ext_vector_type(8))) short bf16x8;
typedef __attribute__((ext_vector_type(4))) float f32x4;

__device__ __forceinline__ unsigned short f2bf(float f) {
    union { float f; unsigned int i; } c; c.f = f;
    unsigned int r = c.i + 0x7fffu + ((c.i >> 16) & 1u);
    return (unsigned short)(r >> 16);
}
__device__ __forceinline__ unsigned cvt_pk(float lo, float hi) {
    unsigned r;
    asm("v_cvt_pk_bf16_f32 %0, %1, %2" : "=v"(r) : "v"(lo), "v"(hi));
    return r;
}
__device__ __forceinline__ float bflo(unsigned u) {
    union { unsigned i; float f; } c; c.i = u << 16; return c.f;
}
__device__ __forceinline__ float bfhi(unsigned u) {
    union { unsigned i; float f; } c; c.i = u & 0xffff0000u; return c.f;
}
__device__ __forceinline__ float silu_f(float v) {
    float t = __builtin_amdgcn_exp2f(-1.44269504f * v);
    return v * __builtin_amdgcn_rcpf(1.0f + t);
}
__device__ __forceinline__ float sigmoid_f(float v) {
    return __builtin_amdgcn_rcpf(1.0f + __builtin_amdgcn_exp2f(-1.44269504f * v));
}
typedef __fp16 fp16x2 __attribute__((ext_vector_type(2)));
__device__ __forceinline__ unsigned pkrtz(float lo, float hi) {
    union { fp16x2 h; unsigned u; } cv;
    cv.h = __builtin_amdgcn_cvt_pkrtz(lo, hi);
    return cv.u;
}
// volatile, no memory clobber: compiler may overlap L3 with the drain
__device__ __forceinline__ void atomic_pk_add_f16_raw(void* p, unsigned u) {
    unsigned long long a = (unsigned long long)p;
    asm volatile("global_atomic_pk_add_f16 %0, %1, off" :: "v"(a), "v"(u));
}

// ---------------------------------------------------------------------------
// Weight prep: A-fragments of W^T (unchanged mapping).
// ---------------------------------------------------------------------------
__global__ __launch_bounds__(256) void egnn_prep(
    const float* __restrict__ We1, const float* __restrict__ We2,
    const float* __restrict__ Wc1, const float* __restrict__ Wn1,
    const float* __restrict__ Wn2,
    short* __restrict__ We1p, short* __restrict__ We2p, short* __restrict__ Wc1p,
    short* __restrict__ Wn1p, short* __restrict__ Wn2p)
{
    int t = blockIdx.x * 256 + threadIdx.x;
    int frag = t >> 6, lane = t & 63;
    if (frag >= 224) return;
    const float* W; short* dst; int KC, f;
    if (frag < 64)       { W = We1; dst = We1p; KC = 8; f = frag; }
    else if (frag < 96)  { W = We2; dst = We2p; KC = 4; f = frag - 64; }
    else if (frag < 128) { W = Wc1; dst = Wc1p; KC = 4; f = frag - 96; }
    else if (frag < 192) { W = Wn1; dst = Wn1p; KC = 8; f = frag - 128; }
    else                 { W = Wn2; dst = Wn2p; KC = 4; f = frag - 192; }
    int nt = f / KC, kc = f % KC;
    int n = nt * 16 + (lane & 15);
    short* d = dst + (((size_t)nt * KC + kc) * 64 + lane) * 8;
    #pragma unroll
    for (int j = 0; j < 8; ++j) {
        int k = kc * 32 + ((lane >> 4) << 2) + (j & 3) + ((j >> 2) << 4);
        d[j] = (short)f2bf(W[(size_t)k * HID + n]);
    }
}

// ---- h -> bf16 pack ----
__global__ __launch_bounds__(256) void egnn_hpack(
    const float* __restrict__ h, short* __restrict__ h16, int N)
{
    int t = blockIdx.x * 256 + threadIdx.x;
    if (t < N * 32) {
        float4 v = *(const float4*)(h + (size_t)t * 4);
        uint2 p; p.x = cvt_pk(v.x, v.y); p.y = cvt_pk(v.z, v.w);
        *(uint2*)(h16 + (size_t)t * 4) = p;
    }
}

// ---------------------------------------------------------------------------
// Edge kernel: 64 edges/block, 4 waves; wave w owns edges w*16..w*16+15.
// NO input staging: B-fragments loaded directly from h16 (lanes g=0..3 form
// contiguous 32B segments). LDS only for const vectors + 16KB f16 scatter
// relay. One barrier total. Natural register allocation (no min-wave bound).
// ---------------------------------------------------------------------------
__global__ __launch_bounds__(256) void egnn_edge_mfma(
    const short* __restrict__ h16, const float* __restrict__ x,
    const int* __restrict__ ei, int E,
    const short* __restrict__ We1p, const float* __restrict__ We1,
    const float* __restrict__ be1,
    const short* __restrict__ We2p, const float* __restrict__ be2,
    const float* __restrict__ Wg, const float* __restrict__ bg,
    const short* __restrict__ Wc1p, const float* __restrict__ bc1,
    const float* __restrict__ Wc2, const float* __restrict__ bc2,
    short* __restrict__ m16, float* __restrict__ coord_aggr)
{
    __shared__ short sRelay[64 * 128];          // 16KB: [64 edges][128 f16], XOR-swizzled
    __shared__ float s_be1[128], s_w256[128], s_be2[128];
    __shared__ float s_wg[128], s_bc1[128], s_wc2[128];

    const int tid  = threadIdx.x;
    const int lane = tid & 63;
    const int w    = tid >> 6;
    const int l15  = lane & 15;
    const int g    = lane >> 4;
    const int e0   = blockIdx.x * 64;
    const int ne   = min(64, E - e0);

    if (tid < 128) {
        s_be1[tid]  = be1[tid];
        s_w256[tid] = We1[(size_t)256 * HID + tid];
        s_be2[tid]  = be2[tid];
        s_wg[tid]   = Wg[tid];
        s_bc1[tid]  = bc1[tid];
        s_wc2[tid]  = Wc2[tid];
    }

    // ---- per-lane edge indices + geometry (direct global reads)
    const int eloc = w * 16 + l15;
    const int eg   = e0 + ((eloc < ne) ? eloc : 0);
    const int nr   = ei[eg];
    const int nc   = ei[E + eg];
    float dx = x[nc * 3 + 0] - x[nr * 3 + 0];
    float dy = x[nc * 3 + 1] - x[nr * 3 + 1];
    float dz = x[nc * 3 + 2] - x[nr * 3 + 2];
    float dist = sqrtf(dx * dx + dy * dy + dz * dz);

    // ---- B-fragments directly from h16: kc<4 -> h[col], kc>=4 -> h[row]
    bf16x8 b[8];
    {
        const short* pc = h16 + (size_t)nc * HID + g * 4;
        const short* pr = h16 + (size_t)nr * HID + g * 4;
        #pragma unroll
        for (int kc = 0; kc < 4; ++kc) {
            ((uint2*)&b[kc])[0] = *(const uint2*)(pc + kc * 32);
            ((uint2*)&b[kc])[1] = *(const uint2*)(pc + kc * 32 + 16);
        }
        #pragma unroll
        for (int kc = 0; kc < 4; ++kc) {
            ((uint2*)&b[4 + kc])[0] = *(const uint2*)(pr + kc * 32);
            ((uint2*)&b[4 + kc])[1] = *(const uint2*)(pr + kc * 32 + 16);
        }
    }
    __syncthreads();    // consts ready (only barrier in the kernel)

    const bf16x8* A1 = (const bf16x8*)We1p;
    const bf16x8* A2 = (const bf16x8*)We2p;
    const bf16x8* A3 = (const bf16x8*)Wc1p;

    // ---- L1: K=256, mt-pair loop; output packed bf16 Bn[4]
    bf16x8 Bn[4];
    #pragma unroll
    for (int j = 0; j < 4; ++j) {
        int f0 = (2 * j) * 16 + g * 4;
        int f1 = f0 + 16;
        f32x4 aa, ab;
        #pragma unroll
        for (int r = 0; r < 4; ++r) {
            aa[r] = s_be1[f0 + r] + dist * s_w256[f0 + r];
            ab[r] = s_be1[f1 + r] + dist * s_w256[f1 + r];
        }
        #pragma unroll
        for (int kc = 0; kc < 8; ++kc) {
            aa = __builtin_amdgcn_mfma_f32_16x16x32_bf16(A1[((2 * j) * 8 + kc) * 64 + lane], b[kc], aa, 0, 0, 0);
            ab = __builtin_amdgcn_mfma_f32_16x16x32_bf16(A1[((2 * j + 1) * 8 + kc) * 64 + lane], b[kc], ab, 0, 0, 0);
        }
        unsigned* d = (unsigned*)&Bn[j];
        d[0] = cvt_pk(silu_f(aa[0]), silu_f(aa[1]));
        d[1] = cvt_pk(silu_f(aa[2]), silu_f(aa[3]));
        d[2] = cvt_pk(silu_f(ab[0]), silu_f(ab[1]));
        d[3] = cvt_pk(silu_f(ab[2]), silu_f(ab[3]));
    }

    // ---- L2: K=128, mt-pair loop; packed UNGATED bf16 Pn[4] + gate dot
    bf16x8 Pn[4];
    float gp = 0.f;
    #pragma unroll
    for (int j = 0; j < 4; ++j) {
        int f0 = (2 * j) * 16 + g * 4;
        int f1 = f0 + 16;
        f32x4 aa, ab;
        #pragma unroll
        for (int r = 0; r < 4; ++r) { aa[r] = s_be2[f0 + r]; ab[r] = s_be2[f1 + r]; }
        #pragma unroll
        for (int kc = 0; kc < 4; ++kc) {
            aa = __builtin_amdgcn_mfma_f32_16x16x32_bf16(A2[((2 * j) * 4 + kc) * 64 + lane], Bn[kc], aa, 0, 0, 0);
            ab = __builtin_amdgcn_mfma_f32_16x16x32_bf16(A2[((2 * j + 1) * 4 + kc) * 64 + lane], Bn[kc], ab, 0, 0, 0);
        }
        float sv[8];
        #pragma unroll
        for (int r = 0; r < 4; ++r) {
            sv[r]     = silu_f(aa[r]);
            sv[4 + r] = silu_f(ab[r]);
            gp += sv[r] * s_wg[f0 + r] + sv[4 + r] * s_wg[f1 + r];
        }
        unsigned* d = (unsigned*)&Pn[j];
        d[0] = cvt_pk(sv[0], sv[1]);
        d[1] = cvt_pk(sv[2], sv[3]);
        d[2] = cvt_pk(sv[4], sv[5]);
        d[3] = cvt_pk(sv[6], sv[7]);
    }
    gp += __shfl_xor(gp, 16, 64);
    gp += __shfl_xor(gp, 32, 64);
    float gate = sigmoid_f(gp + bg[0]);
    gate *= (eloc < ne) ? 1.0f : 0.0f;      // zero pad-slot payloads

    // ---- gate in packed domain: B3 (bf16) + f16 words to wave-private relay.
    // Relay byte layout per edge row (128 f16 = 256B): feature f at 2f,
    // XOR-swizzled by (e&7)<<4 to spread banks.
    const int swE = (eloc & 7) << 4;
    bf16x8 B3[4];
    #pragma unroll
    for (int j = 0; j < 4; ++j) {
        const unsigned* s = (const unsigned*)&Pn[j];
        unsigned* d = (unsigned*)&B3[j];
        uint2 w0, w1;
        { float lo = bflo(s[0]) * gate, hi = bfhi(s[0]) * gate; d[0] = cvt_pk(lo, hi); w0.x = pkrtz(lo, hi); }
        { float lo = bflo(s[1]) * gate, hi = bfhi(s[1]) * gate; d[1] = cvt_pk(lo, hi); w0.y = pkrtz(lo, hi); }
        { float lo = bflo(s[2]) * gate, hi = bfhi(s[2]) * gate; d[2] = cvt_pk(lo, hi); w1.x = pkrtz(lo, hi); }
        { float lo = bflo(s[3]) * gate, hi = bfhi(s[3]) * gate; d[3] = cvt_pk(lo, hi); w1.y = pkrtz(lo, hi); }
        // features (2j)*16+g*4.. -> bytes (2j)*32+g*8 ; (2j+1): +32
        *(uint2*)((char*)sRelay + eloc * 256 + (((2 * j) * 32 + g * 8) ^ swE))     = w0;
        *(uint2*)((char*)sRelay + eloc * 256 + (((2 * j + 1) * 32 + g * 8) ^ swE)) = w1;
    }

    // ---- dense m scatter via relay: per edge, 64 lanes read its 256B row
    // and issue one pk-f16 atomic each -> 4 fully-covered lines/edge.
    // Rows [w*16, w*16+16) are wave-private: no barrier needed.
    #pragma unroll
    for (int i = 0; i < 16; ++i) {
        int e = w * 16 + i;
        int c = __shfl(nc, e & 15, 16);     // broadcast col of edge e from lane i (same wave)
        int sws = (e & 7) << 4;
        unsigned v = *(const unsigned*)((const char*)sRelay + e * 256 + ((lane * 4) ^ sws));
        if (e0 + e < E)
            atomic_pk_add_f16_raw(m16 + (size_t)c * HID + lane * 2, v);
    }

    // ---- L3: K=128, mt-pair loop; consume into coord-weight dot
    float cwp = 0.f;
    #pragma unroll
    for (int j = 0; j < 4; ++j) {
        int f0 = (2 * j) * 16 + g * 4;
        int f1 = f0 + 16;
        f32x4 aa, ab;
        #pragma unroll
        for (int r = 0; r < 4; ++r) { aa[r] = s_bc1[f0 + r]; ab[r] = s_bc1[f1 + r]; }
        #pragma unroll
        for (int kc = 0; kc < 4; ++kc) {
            aa = __builtin_amdgcn_mfma_f32_16x16x32_bf16(A3[((2 * j) * 4 + kc) * 64 + lane], B3[kc], aa, 0, 0, 0);
            ab = __builtin_amdgcn_mfma_f32_16x16x32_bf16(A3[((2 * j + 1) * 4 + kc) * 64 + lane], B3[kc], ab, 0, 0, 0);
        }
        #pragma unroll
        for (int r = 0; r < 4; ++r)
            cwp += silu_f(aa[r]) * s_wc2[f0 + r] + silu_f(ab[r]) * s_wc2[f1 + r];
    }
    cwp += __shfl_xor(cwp, 16, 64);
    cwp += __shfl_xor(cwp, 32, 64);
    float cw = cwp + bc2[0];
    if (g == 0 && eloc < ne) {
        atomicAdd(&coord_aggr[nc * 3 + 0], dx * cw);
        atomicAdd(&coord_aggr[nc * 3 + 1], dy * cw);
        atomicAdd(&coord_aggr[nc * 3 + 2], dz * cw);
    }
}

// ---------------------------------------------------------------------------
// Node kernel: transposed structure, 64 nodes/block (unchanged).
// ---------------------------------------------------------------------------
__global__ __launch_bounds__(256) void egnn_node_mfma(
    const float* __restrict__ h, const short* __restrict__ h16,
    const float* __restrict__ x,
    const short* __restrict__ m16, const float* __restrict__ coord_aggr,
    const short* __restrict__ Wn1p, const float* __restrict__ bn1,
    const short* __restrict__ Wn2p, const float* __restrict__ bn2,
    float* __restrict__ h_out, float* __restrict__ x_out, int N)
{
    __shared__ short sStage[64 * 256];
    __shared__ float s_bn1[128], s_bn2[128];

    const int tid  = threadIdx.x;
    const int lane = tid & 63;
    const int w    = tid >> 6;
    const int l15  = lane & 15;
    const int g    = lane >> 4;
    const int n0   = blockIdx.x * 64;

    if (tid < 128) { s_bn1[tid] = bn1[tid]; s_bn2[tid] = bn2[tid]; }

    if (tid < 192) {
        int gi = n0 * 3 + tid;
        if (gi < 3 * N) x_out[gi] = x[gi] + coord_aggr[gi];
    }

    #pragma unroll
    for (int it = 0; it < 16; ++it) {
        int e = w + 4 * it;
        int q = lane;
        int node = min(n0 + e, N - 1);
        uint2 pk;
        if (q < 32) {
            pk = *(const uint2*)(h16 + (size_t)node * HID + (size_t)q * 4);
        } else {
            uint2 hv = *(const uint2*)((const char*)m16 + (size_t)node * 256 + (size_t)(q & 31) * 8);
            const __fp16* hp = (const __fp16*)&hv;
            pk.x = cvt_pk((float)hp[0], (float)hp[1]);
            pk.y = cvt_pk((float)hp[2], (float)hp[3]);
        }
        *(uint2*)((char*)sStage + e * 512 + ((q * 8) ^ ((e & 7) << 4))) = pk;
    }
    __syncthreads();

    const int nloc = w * 16 + l15;
    const int node = n0 + nloc;
    const char* stageRow = (const char*)sStage + nloc * 512;
    const int sw = (nloc & 7) << 4;
    const bf16x8* A1 = (const bf16x8*)Wn1p;
    const bf16x8* A2 = (const bf16x8*)Wn2p;

    f32x4 acc[8];
    #pragma unroll
    for (int mt = 0; mt < 8; ++mt) {
        int f = mt * 16 + g * 4;
        #pragma unroll
        for (int r = 0; r < 4; ++r) acc[mt][r] = s_bn1[f + r];
    }
    #pragma unroll
    for (int kc = 0; kc < 8; ++kc) {
        int kb = kc * 64 + g * 8;
        uint2 lo = *(const uint2*)(stageRow + ((kb     ) ^ sw));
        uint2 hi = *(const uint2*)(stageRow + ((kb + 32) ^ sw));
        bf16x8 b; ((uint2*)&b)[0] = lo; ((uint2*)&b)[1] = hi;
        #pragma unroll
        for (int mt = 0; mt < 8; ++mt)
            acc[mt] = __builtin_amdgcn_mfma_f32_16x16x32_bf16(A1[(mt * 8 + kc) * 64 + lane], b, acc[mt], 0, 0, 0);
    }

    bf16x8 Bn[4];
    #pragma unroll
    for (int kc = 0; kc < 4; ++kc) {
        unsigned* d = (unsigned*)&Bn[kc];
        d[0] = cvt_pk(silu_f(acc[2 * kc][0]),     silu_f(acc[2 * kc][1]));
        d[1] = cvt_pk(silu_f(acc[2 * kc][2]),     silu_f(acc[2 * kc][3]));
        d[2] = cvt_pk(silu_f(acc[2 * kc + 1][0]), silu_f(acc[2 * kc + 1][1]));
        d[3] = cvt_pk(silu_f(acc[2 * kc + 1][2]), silu_f(acc[2 * kc + 1][3]));
    }

    f32x4 acc2[8];
    #pragma unroll
    for (int mt = 0; mt < 8; ++mt) {
        int f = mt * 16 + g * 4;
        #pragma unroll
        for (int r = 0; r < 4; ++r) acc2[mt][r] = s_bn2[f + r];
    }
    #pragma unroll
    for (int kc = 0; kc < 4; ++kc)
        #pragma unroll
        for (int mt = 0; mt < 8; ++mt)
            acc2[mt] = __builtin_amdgcn_mfma_f32_16x16x32_bf16(A2[(mt * 4 + kc) * 64 + lane], Bn[kc], acc2[mt], 0, 0, 0);

    if (node < N) {
        #pragma unroll
        for (int mt = 0; mt < 8; ++mt) {
            size_t base = (size_t)node * HID + mt * 16 + g * 4;
            float4 hres = *(const float4*)&h[base];
            float4 o;
            o.x = acc2[mt][0] + hres.x;
            o.y = acc2[mt][1] + hres.y;
            o.z = acc2[mt][2] + hres.z;
            o.w = acc2[mt][3] + hres.w;
            *(float4*)&h_out[base] = o;
        }
    }
}

extern "C" void kernel_launch(void* const* d_in, const int* in_sizes, int n_in,
                              void* d_out, int out_size, void* d_ws, size_t ws_size,
                              hipStream_t stream) {
    const float* h   = (const float*)d_in[0];
    const float* x   = (const float*)d_in[1];
    const int*   ei  = (const int*)d_in[2];
    const float* We1 = (const float*)d_in[3];
    const float* be1 = (const float*)d_in[4];
    const float* We2 = (const float*)d_in[5];
    const float* be2 = (const float*)d_in[6];
    const float* Wg  = (const float*)d_in[7];
    const float* bg  = (const float*)d_in[8];
    const float* Wn1 = (const float*)d_in[9];
    const float* bn1 = (const float*)d_in[10];
    const float* Wn2 = (const float*)d_in[11];
    const float* bn2 = (const float*)d_in[12];
    const float* Wc1 = (const float*)d_in[13];
    const float* bc1 = (const float*)d_in[14];
    const float* Wc2 = (const float*)d_in[15];
    const float* bc2 = (const float*)d_in[16];

    const int N = in_sizes[0] / HID;
    const int E = in_sizes[2] / 2;

    // workspace layout
    char* p = (char*)d_ws;
    short* m16        = (short*)p;  p += (size_t)N * 256;   // N*128 f16
    float* coord_aggr = (float*)p;  p += (size_t)N * 12;    // N*3 f32
    // ---- memset covers [d_ws, p) = N*268 bytes ----
    short* h16        = (short*)p;  p += (size_t)N * 256;   // N*128 bf16
    short* We1p       = (short*)p;  p += 256 * 128 * 2;
    short* We2p       = (short*)p;  p += 128 * 128 * 2;
    short* Wc1p       = (short*)p;  p += 128 * 128 * 2;
    short* Wn1p       = (short*)p;  p += 256 * 128 * 2;
    short* Wn2p       = (short*)p;  p += 128 * 128 * 2;

    (void)hipMemsetAsync(d_ws, 0, (size_t)N * 268, stream);

    float* h_out = (float*)d_out;
    float* x_out = h_out + (size_t)N * HID;

    egnn_prep<<<dim3(56), dim3(256), 0, stream>>>(
        We1, We2, Wc1, Wn1, Wn2, We1p, We2p, Wc1p, Wn1p, Wn2p);
    egnn_hpack<<<dim3((N * 32 + 255) / 256), dim3(256), 0, stream>>>(h, h16, N);
    egnn_edge_mfma<<<dim3((E + 63) / 64), dim3(256), 0, stream>>>(
        h16, x, ei, E, We1p, We1, be1, We2p, be2, Wg, bg, Wc1p, bc1, Wc2, bc2,
        m16, coord_aggr);
    egnn_node_mfma<<<dim3((N + 63) / 64), dim3(256), 0, stream>>>(
        h, h16, x, m16, coord_aggr, Wn1p, bn1, Wn2p, bn2, h_out, x_out, N);
}